// Round 1
// baseline (180.472 us; speedup 1.0000x reference)
//
#include <hip/hip_runtime.h>
#include <hip/hip_bf16.h>
#include <stdint.h>

#define S_SEQ 128
#define N_RES 256
#define CMDIM 256
#define C_SM  32
#define C_Z   128

typedef __attribute__((ext_vector_type(8))) short bf16x8;
typedef __attribute__((ext_vector_type(4))) float f32x4;
typedef __attribute__((ext_vector_type(4))) unsigned int u32x4;
typedef __attribute__((ext_vector_type(2))) unsigned int u32x2;

__device__ __forceinline__ unsigned short f32_to_bf16(float f) {
    union { float f; unsigned int u; } v; v.f = f;
    unsigned int u = v.u;
    return (unsigned short)((u + 0x7FFFu + ((u >> 16) & 1u)) >> 16);
}

// ---------------- K0: convert weights to bf16 ----------------
// Wbf[64][256]: rows 0-31 = w1, rows 32-63 = w2. wobf[128][1024].
__global__ __launch_bounds__(256) void k_prep(
    const float* __restrict__ w1, const float* __restrict__ w2,
    const float* __restrict__ wo,
    unsigned short* __restrict__ Wbf, unsigned short* __restrict__ wobf)
{
    int t = blockIdx.x * 256 + threadIdx.x;
    if (t < 16384) {
        float v = (t < 8192) ? w1[t] : w2[t - 8192];
        Wbf[t] = f32_to_bf16(v);
    }
    if (t < 131072) wobf[t] = f32_to_bf16(wo[t]);
}

// ---------------- K1: LayerNorm + dual projection ----------------
// One WG per i (256 WGs). Wave w does LN for s in [w*32, w*32+32), writes
// bf16 mn rows into swizzled LDS, then MFMA D[ch][s] = W * mn^T for its own
// s-range. Stores A2[(i*32+c)*128+s], B2[(i*32+d)*128+s] (K-transposed).
__global__ __launch_bounds__(256) void k_ln_proj(
    const float* __restrict__ m, const float* __restrict__ lnw, const float* __restrict__ lnb,
    const float* __restrict__ b1, const float* __restrict__ b2,
    const unsigned short* __restrict__ Wbf,
    unsigned short* __restrict__ A2, unsigned short* __restrict__ B2)
{
    __shared__ unsigned short mn[128 * 256];   // 64 KB, rows of 512 B, 16B-chunk XOR swizzle
    int i = blockIdx.x;
    int tid = threadIdx.x;
    int wv = tid >> 6, lane = tid & 63;
    int quad = lane >> 4, l15 = lane & 15;

    f32x4 lw = *(const f32x4*)(lnw + lane * 4);
    f32x4 lb = *(const f32x4*)(lnb + lane * 4);

    for (int r = 0; r < 32; ++r) {
        int s = wv * 32 + r;
        const float* row = m + ((size_t)s * N_RES + i) * CMDIM;
        f32x4 x = *(const f32x4*)(row + lane * 4);
        float s1 = x[0] + x[1] + x[2] + x[3];
        float s2 = x[0]*x[0] + x[1]*x[1] + x[2]*x[2] + x[3]*x[3];
        #pragma unroll
        for (int off = 32; off; off >>= 1) {
            s1 += __shfl_xor(s1, off);
            s2 += __shfl_xor(s2, off);
        }
        float mu = s1 * (1.0f / 256.0f);
        float var = s2 * (1.0f / 256.0f) - mu * mu;
        float rstd = rsqrtf(var + 1e-5f);
        float n0 = (x[0] - mu) * rstd * lw[0] + lb[0];
        float n1 = (x[1] - mu) * rstd * lw[1] + lb[1];
        float n2 = (x[2] - mu) * rstd * lw[2] + lb[2];
        float n3 = (x[3] - mu) * rstd * lw[3] + lb[3];
        unsigned int p0 = (unsigned)f32_to_bf16(n0) | ((unsigned)f32_to_bf16(n1) << 16);
        unsigned int p1 = (unsigned)f32_to_bf16(n2) | ((unsigned)f32_to_bf16(n3) << 16);
        int chunk = lane >> 1;                       // 16B chunk index 0..31
        int pos = (chunk & 16) | ((chunk ^ s) & 15); // XOR swizzle low 4 bits
        unsigned int* dst = (unsigned int*)((char*)mn + s * 512 + pos * 16 + (lane & 1) * 8);
        dst[0] = p0; dst[1] = p1;
    }
    __syncthreads();

    // MFMA: wave wv covers cols s in [wv*32, wv*32+32)
    f32x4 acc[4][2];
    #pragma unroll
    for (int a = 0; a < 4; ++a)
        #pragma unroll
        for (int b = 0; b < 2; ++b) acc[a][b] = (f32x4){0.f, 0.f, 0.f, 0.f};

    #pragma unroll
    for (int ks = 0; ks < 8; ++ks) {
        bf16x8 af[4], bfr[2];
        #pragma unroll
        for (int mb = 0; mb < 4; ++mb) {
            int ch = mb * 16 + l15;
            af[mb] = *(const bf16x8*)(Wbf + ch * 256 + ks * 32 + quad * 8);
        }
        #pragma unroll
        for (int nb = 0; nb < 2; ++nb) {
            int srow = wv * 32 + nb * 16 + l15;
            int q = ks * 4 + quad;                       // chunk 0..31
            int pos = (q & 16) | ((q ^ srow) & 15);
            bfr[nb] = *(const bf16x8*)((char*)mn + srow * 512 + pos * 16);
        }
        #pragma unroll
        for (int mb = 0; mb < 4; ++mb)
            #pragma unroll
            for (int nb = 0; nb < 2; ++nb)
                acc[mb][nb] = __builtin_amdgcn_mfma_f32_16x16x32_bf16(af[mb], bfr[nb], acc[mb][nb], 0, 0, 0);
    }

    // store: row of C = ch (quad*4+reg), col = s (l15)
    #pragma unroll
    for (int mb = 0; mb < 4; ++mb) {
        const float* bsrc = (mb < 2) ? b1 : b2;
        f32x4 bias = *(const f32x4*)(bsrc + (mb & 1) * 16 + quad * 4);
        unsigned short* dst = (mb < 2) ? A2 : B2;
        #pragma unroll
        for (int nb = 0; nb < 2; ++nb) {
            int s = wv * 32 + nb * 16 + l15;
            #pragma unroll
            for (int reg = 0; reg < 4; ++reg) {
                int ch = (mb & 1) * 16 + quad * 4 + reg;   // 0..31 within a/b
                float v = acc[mb][nb][reg] + bias[reg];
                dst[((size_t)(i * 32 + ch)) * 128 + s] = f32_to_bf16(v);
            }
        }
    }
}

// ---------------- K3: GEMM-1  o^T tile ----------------
// D[m'=(j,d)][n'=(i,c)] = sum_s B2[m'][s]*A2[n'][s]; K=128 single shot.
// Writes o[(i*Jc+jl)*1024 + c*32 + d] bf16, 4 d-consecutive packed per store.
__global__ __launch_bounds__(256) void k_gemm1(
    const unsigned short* __restrict__ A2, const unsigned short* __restrict__ B2,
    unsigned short* __restrict__ ows, int j0, int Jc)
{
    __shared__ unsigned short Tm[128 * 128];  // B2 rows (m'), 32 KB, swizzled
    __shared__ unsigned short Tn[128 * 128];  // A2 rows (n')
    int bx = blockIdx.x;       // n' tile
    int by = blockIdx.y;       // m' tile within chunk
    int tid = threadIdx.x, wv = tid >> 6, lane = tid & 63;
    int quad = lane >> 4, l15 = lane & 15;

    const unsigned short* srcM = B2 + ((size_t)(j0 * 32 + by * 128)) * 128;
    const unsigned short* srcN = A2 + ((size_t)(bx * 128)) * 128;
    #pragma unroll
    for (int it = 0; it < 8; ++it) {
        int r = it * 16 + wv * 4 + (lane >> 4);
        int c = lane & 15;
        int pos = c ^ (r & 15);
        u32x4 vm = *(const u32x4*)(srcM + r * 128 + c * 8);
        u32x4 vn = *(const u32x4*)(srcN + r * 128 + c * 8);
        *(u32x4*)((char*)Tm + r * 256 + pos * 16) = vm;
        *(u32x4*)((char*)Tn + r * 256 + pos * 16) = vn;
    }
    __syncthreads();

    int wm = wv & 1, wn = wv >> 1;
    f32x4 acc[4][4];
    #pragma unroll
    for (int a = 0; a < 4; ++a)
        #pragma unroll
        for (int b = 0; b < 4; ++b) acc[a][b] = (f32x4){0.f, 0.f, 0.f, 0.f};

    #pragma unroll
    for (int ks = 0; ks < 4; ++ks) {
        bf16x8 am[4], bn[4];
        #pragma unroll
        for (int mb = 0; mb < 4; ++mb) {
            int r = wm * 64 + mb * 16 + l15;
            int q = ks * 4 + quad;
            int pos = q ^ (r & 15);
            am[mb] = *(const bf16x8*)((char*)Tm + r * 256 + pos * 16);
        }
        #pragma unroll
        for (int nb = 0; nb < 4; ++nb) {
            int r = wn * 64 + nb * 16 + l15;
            int q = ks * 4 + quad;
            int pos = q ^ (r & 15);
            bn[nb] = *(const bf16x8*)((char*)Tn + r * 256 + pos * 16);
        }
        #pragma unroll
        for (int mb = 0; mb < 4; ++mb)
            #pragma unroll
            for (int nb = 0; nb < 4; ++nb)
                acc[mb][nb] = __builtin_amdgcn_mfma_f32_16x16x32_bf16(am[mb], bn[nb], acc[mb][nb], 0, 0, 0);
    }

    #pragma unroll
    for (int mb = 0; mb < 4; ++mb) {
        int mloc = by * 128 + wm * 64 + mb * 16 + quad * 4;   // (jl,d) base; regs give d..d+3
        int jl = mloc >> 5, d = mloc & 31;
        #pragma unroll
        for (int nb = 0; nb < 4; ++nb) {
            int ng = bx * 128 + wn * 64 + nb * 16 + l15;      // (i,c)
            int ii = ng >> 5, cc = ng & 31;
            f32x4 a4 = acc[mb][nb];
            unsigned int p0 = (unsigned)f32_to_bf16(a4[0]) | ((unsigned)f32_to_bf16(a4[1]) << 16);
            unsigned int p1 = (unsigned)f32_to_bf16(a4[2]) | ((unsigned)f32_to_bf16(a4[3]) << 16);
            u32x2 pv = {p0, p1};
            *(u32x2*)(ows + (((size_t)(ii * Jc + jl)) << 10) + cc * 32 + d) = pv;
        }
    }
}

// ---------------- K4: GEMM-2  z = (o . wo^T + bo)/128 ----------------
// D[zo][n=(i,jl)] = sum_k wobf[zo][k]*o[n][k]; K=1024, BK=64.
__global__ __launch_bounds__(256) void k_gemm2(
    const unsigned short* __restrict__ wobf, const unsigned short* __restrict__ ows,
    const float* __restrict__ bo, float* __restrict__ out,
    int j0, int jshift)
{
    __shared__ unsigned short Ta[128 * 64];   // wo tile (zo rows), 16 KB
    __shared__ unsigned short Tb[128 * 64];   // o tile (n rows), 16 KB
    int bx = blockIdx.x;
    int tid = threadIdx.x, wv = tid >> 6, lane = tid & 63;
    int quad = lane >> 4, l15 = lane & 15;
    int wm = wv & 1, wn = wv >> 1;
    int n0 = bx * 128;
    const unsigned short* srcB = ows + ((size_t)n0) * 1024;

    f32x4 acc[4][4];
    #pragma unroll
    for (int a = 0; a < 4; ++a)
        #pragma unroll
        for (int b = 0; b < 4; ++b) acc[a][b] = (f32x4){0.f, 0.f, 0.f, 0.f};

    for (int kt = 0; kt < 16; ++kt) {
        __syncthreads();
        #pragma unroll
        for (int it = 0; it < 4; ++it) {
            int r = it * 32 + wv * 8 + (lane >> 3);
            int c = lane & 7;
            int pos = c ^ (r & 7);
            u32x4 va = *(const u32x4*)(wobf + (size_t)r * 1024 + kt * 64 + c * 8);
            u32x4 vb = *(const u32x4*)(srcB + (size_t)r * 1024 + kt * 64 + c * 8);
            *(u32x4*)((char*)Ta + r * 128 + pos * 16) = va;
            *(u32x4*)((char*)Tb + r * 128 + pos * 16) = vb;
        }
        __syncthreads();
        #pragma unroll
        for (int ks = 0; ks < 2; ++ks) {
            bf16x8 am[4], bn[4];
            #pragma unroll
            for (int mb = 0; mb < 4; ++mb) {
                int r = wm * 64 + mb * 16 + l15;
                int q = ks * 4 + quad;
                int pos = q ^ (r & 7);
                am[mb] = *(const bf16x8*)((char*)Ta + r * 128 + pos * 16);
            }
            #pragma unroll
            for (int nb = 0; nb < 4; ++nb) {
                int r = wn * 64 + nb * 16 + l15;
                int q = ks * 4 + quad;
                int pos = q ^ (r & 7);
                bn[nb] = *(const bf16x8*)((char*)Tb + r * 128 + pos * 16);
            }
            #pragma unroll
            for (int mb = 0; mb < 4; ++mb)
                #pragma unroll
                for (int nb = 0; nb < 4; ++nb)
                    acc[mb][nb] = __builtin_amdgcn_mfma_f32_16x16x32_bf16(am[mb], bn[nb], acc[mb][nb], 0, 0, 0);
        }
    }

    int jmask = (1 << jshift) - 1;
    #pragma unroll
    for (int mb = 0; mb < 4; ++mb) {
        int zo = wm * 64 + mb * 16 + quad * 4;
        f32x4 b4 = *(const f32x4*)(bo + zo);
        #pragma unroll
        for (int nb = 0; nb < 4; ++nb) {
            int nl = n0 + wn * 64 + nb * 16 + l15;
            int ii = nl >> jshift;
            int j = j0 + (nl & jmask);
            f32x4 v;
            #pragma unroll
            for (int reg = 0; reg < 4; ++reg)
                v[reg] = (acc[mb][nb][reg] + b4[reg]) * (1.0f / 128.0f);
            *(f32x4*)(out + ((size_t)(ii * 256 + j)) * 128 + zo) = v;
        }
    }
}

extern "C" void kernel_launch(void* const* d_in, const int* in_sizes, int n_in,
                              void* d_out, int out_size, void* d_ws, size_t ws_size,
                              hipStream_t stream) {
    const float* m   = (const float*)d_in[0];
    const float* lnw = (const float*)d_in[1];
    const float* lnb = (const float*)d_in[2];
    const float* w1  = (const float*)d_in[3];
    const float* b1  = (const float*)d_in[4];
    const float* w2  = (const float*)d_in[5];
    const float* b2  = (const float*)d_in[6];
    const float* wo  = (const float*)d_in[7];
    const float* bo  = (const float*)d_in[8];
    float* out = (float*)d_out;
    char* ws = (char*)d_ws;

    unsigned short* Wbf  = (unsigned short*)(ws);
    unsigned short* wobf = (unsigned short*)(ws + 32768);
    unsigned short* A2   = (unsigned short*)(ws + 32768 + 262144);
    unsigned short* B2   = (unsigned short*)(ws + 32768 + 262144 + 2097152);
    unsigned short* ows  = (unsigned short*)(ws + 32768 + 262144 + 2 * 2097152);
    const size_t obase = 32768 + 262144 + 2 * 2097152;   // 4489216 B

    int Jc = 4;
    for (int c = 256; c >= 4; c >>= 1) {
        if (obase + (size_t)c * 524288 <= ws_size) { Jc = c; break; }
    }
    int jshift = __builtin_ctz(Jc);

    hipLaunchKernelGGL(k_prep, dim3(512), dim3(256), 0, stream, w1, w2, wo, Wbf, wobf);
    hipLaunchKernelGGL(k_ln_proj, dim3(256), dim3(256), 0, stream,
                       m, lnw, lnb, b1, b2, Wbf, A2, B2);
    for (int j0 = 0; j0 < 256; j0 += Jc) {
        hipLaunchKernelGGL(k_gemm1, dim3(64, Jc / 4), dim3(256), 0, stream,
                           A2, B2, ows, j0, Jc);
        hipLaunchKernelGGL(k_gemm2, dim3(2 * Jc), dim3(256), 0, stream,
                           wobf, ows, bo, out, j0, jshift);
    }
}